// Round 3
// baseline (1802.865 us; speedup 1.0000x reference)
//
#include <hip/hip_runtime.h>
#include <cstdint>
#include <cstddef>

// R2: 512 WGs x 512 threads, ONE row per WG (k-split 4: kq=t&3, oq=t>>2).
// VGPR pinned <=128 via __launch_bounds__(512,4) -> 4 waves/SIMD -> 2 WGs/CU.
// Two co-resident WGs hide each other's barrier/LDS latency.
// Predicted: ~700-800us, VALUBusy 50-60%, Occupancy ~30%.

typedef _Float16 f16;
typedef _Float16 f16x2 __attribute__((ext_vector_type(2)));

#define NSTEP 127
#define NSUB 10
#define B_LEN 512
#define S_LEN 128
#define H_LEN 128

__device__ __forceinline__ float dot2acc(f16x2 a, f16x2 b, float c) {
  return __builtin_amdgcn_fdot2(a, b, c, false);
}
__device__ __forceinline__ f16x2 bchalf(unsigned int u) {
  return __builtin_bit_cast(f16x2, u);
}

#define DOT4R(acc, wr, base, dv)                          \
  do {                                                    \
    acc = dot2acc((wr)[(base) + 0], bchalf((dv).x), acc); \
    acc = dot2acc((wr)[(base) + 1], bchalf((dv).y), acc); \
    acc = dot2acc((wr)[(base) + 2], bchalf((dv).z), acc); \
    acc = dot2acc((wr)[(base) + 3], bchalf((dv).w), acc); \
  } while (0)

// JAX threefry2x32 (20 rounds) -- bit-exact (verified R0/R1: absmax 9.8e-4).
__device__ __forceinline__ void tf2x32(unsigned int k0, unsigned int k1,
                                       unsigned int& x0, unsigned int& x1) {
  unsigned int ks[3] = {k0, k1, k0 ^ k1 ^ 0x1BD11BDAu};
  x0 += ks[0];
  x1 += ks[1];
  const int R[2][4] = {{13, 15, 26, 6}, {17, 29, 16, 24}};
#pragma unroll
  for (int g = 0; g < 5; ++g) {
#pragma unroll
    for (int j = 0; j < 4; ++j) {
      const int r = R[g & 1][j];
      x0 += x1;
      x1 = (x1 << r) | (x1 >> (32 - r));
      x1 ^= x0;
    }
    x0 += ks[(g + 1) % 3];
    x1 += ks[(g + 2) % 3] + (unsigned int)(g + 1);
  }
}

__device__ __forceinline__ float erfinv_f32(float x) {
  float w = -log1pf(-x * x);
  float p;
  if (w < 5.0f) {
    w = w - 2.5f;
    p = 2.81022636e-08f;
    p = fmaf(p, w, 3.43273939e-07f);
    p = fmaf(p, w, -3.5233877e-06f);
    p = fmaf(p, w, -4.39150654e-06f);
    p = fmaf(p, w, 0.00021858087f);
    p = fmaf(p, w, -0.00125372503f);
    p = fmaf(p, w, -0.00417768164f);
    p = fmaf(p, w, 0.246640727f);
    p = fmaf(p, w, 1.50140941f);
  } else {
    w = sqrtf(w) - 3.0f;
    p = -0.000200214257f;
    p = fmaf(p, w, 0.000100950558f);
    p = fmaf(p, w, 0.00134934322f);
    p = fmaf(p, w, -0.00367342844f);
    p = fmaf(p, w, 0.00573950773f);
    p = fmaf(p, w, -0.0076224613f);
    p = fmaf(p, w, 0.00943887047f);
    p = fmaf(p, w, 1.00167406f);
    p = fmaf(p, w, 2.83297682f);
  }
  return p * x;
}

__device__ __forceinline__ float frcp(float x) {
  return __builtin_amdgcn_rcpf(x);
}
__device__ __forceinline__ float fsig(float x) {
  return frcp(1.0f + __expf(-x));
}
__device__ __forceinline__ float ftanh_fast(float x) {
  return 1.0f - 2.0f * frcp(__expf(2.0f * x) + 1.0f);
}
__device__ __forceinline__ float fsoftplus(float x) {
  return fmaxf(x, 0.0f) + __logf(1.0f + __expf(-fabsf(x)));
}

// ---- td precompute: one block per step i; writes wsTd[i]
__global__ __launch_bounds__(256) void td_kernel(
    const float* __restrict__ times, const int* __restrict__ non_zero,
    float* __restrict__ wsTd) {
  __shared__ float sA[256], sB[256];
  __shared__ int sC[256];
  const int i = blockIdx.x;
  const int t = threadIdx.x;
  float s1 = 0.f, s2 = 0.f;
  int c = 0;
  for (int b = t; b < B_LEN; b += 256) {
    const int nz = non_zero[b];
    const float t1 = times[b * S_LEN + i + 1];
    const bool v = (i < nz - 1) && (t1 != 0.0f);
    if (v) {
      c += 1;
      s1 += times[b * S_LEN + i];
      s2 += t1;
    }
  }
  sA[t] = s1;
  sB[t] = s2;
  sC[t] = c;
  __syncthreads();
  for (int o = 128; o > 0; o >>= 1) {
    if (t < o) {
      sA[t] += sA[t + o];
      sB[t] += sB[t + o];
      sC[t] += sC[t + o];
    }
    __syncthreads();
  }
  if (t == 0) {
    const float cnt = (float)((sC[0] < 1) ? 1 : sC[0]);
    const float ts = sA[0] / cnt * 0.02f;
    const float te = sB[0] / cnt * 0.02f;
    wsTd[i] = (te == ts) ? 1.0f : (te - ts);
  }
}

__global__ __launch_bounds__(512, 4) void sde_fused_kernel(
    const float* __restrict__ inputs, const int* __restrict__ non_zero,
    const float* __restrict__ Wih, const float* __restrict__ Whh,
    const float* __restrict__ bih, const float* __restrict__ bhh,
    const float* __restrict__ dW1, const float* __restrict__ db1,
    const float* __restrict__ dW2, const float* __restrict__ db2,
    const float* __restrict__ gW1, const float* __restrict__ gb1,
    const float* __restrict__ gW2, const float* __restrict__ gb2,
    const float* __restrict__ wsTd, float* __restrict__ out) {
  __shared__ float sZ[NSTEP * NSUB];
  __shared__ float sDt[NSTEP], sSq[NSTEP], sU[NSTEP];
  __shared__ __align__(16) f16 sX[H_LEN];
  __shared__ __align__(16) f16 sH2[H_LEN];
  __shared__ __align__(16) f16 sH[H_LEN];
  __shared__ __align__(16) f16 sAct[H_LEN];

  const int t = threadIdx.x;
  const int kq = t & 3;   // k-quarter; reduce via shfl_xor 1,2 (quad DPP)
  const int oq = t >> 2;  // output index 0..127 (wave-uniform oq<64 split)
  const int kb32 = kq * 32;
  const int kb16 = kq * 16;
  const int b = blockIdx.x;  // one batch row per WG

  const int L = non_zero[b] - 1;

  // ---- noise precompute for this row (same bit-stream as R0/R1)
  for (int idx = t; idx < NSTEP * NSUB; idx += 512) {
    unsigned int f0 = 0u, f1 = (unsigned int)idx;  // idx = i*10+s
    tf2x32(0u, 42u, f0, f1);
    unsigned int y0 = 0u, y1 = (unsigned int)b;
    tf2x32(f0, f1, y0, y1);
    const unsigned int bits = y1;
    const float fl = __uint_as_float((bits >> 9) | 0x3F800000u) - 1.0f;
    const float lo = __uint_as_float(0xBF7FFFFFu);
    float u = fl * (1.0f - lo) + lo;
    u = fmaxf(lo, u);
    sZ[idx] = 1.41421356237f * erfinv_f32(u);
  }
  if (t < NSTEP) {
    const float td = wsTd[t];
    sDt[t] = td * 0.1f;
    sSq[t] = sqrtf(td * 0.1f);
    sU[t] = (t == 0) ? 1.0f : __expf(-wsTd[t - 1]);
  }

  // ---- register weight preload (packed f16, k-quarter slices): 128 VGPRs
  f16x2 rWih[3][16], rWhh[3][16];
#pragma unroll
  for (int g = 0; g < 3; ++g) {
    const float* pi = Wih + (size_t)(oq + 128 * g) * 128 + kb32;
    const float* ph = Whh + (size_t)(oq + 128 * g) * 128 + kb32;
#pragma unroll
    for (int c = 0; c < 16; ++c) {
      f16x2 a;
      a[0] = (f16)pi[2 * c];
      a[1] = (f16)pi[2 * c + 1];
      rWih[g][c] = a;
      f16x2 bb;
      bb[0] = (f16)ph[2 * c];
      bb[1] = (f16)ph[2 * c + 1];
      rWhh[g][c] = bb;
    }
  }
  f16x2 rW1[16];
  {
    const float* p1 = (oq < 64) ? (dW1 + (size_t)oq * 128 + kb32)
                                : (gW1 + (size_t)(oq - 64) * 128 + kb32);
#pragma unroll
    for (int c = 0; c < 16; ++c) {
      f16x2 a;
      a[0] = (f16)p1[2 * c];
      a[1] = (f16)p1[2 * c + 1];
      rW1[c] = a;
    }
  }
  f16x2 rW2d[8], rW2g[8];
  {
    const float* pd = dW2 + (size_t)oq * 64 + kb16;
    const float* pg = gW2 + (size_t)oq * 64 + kb16;
#pragma unroll
    for (int c = 0; c < 8; ++c) {
      f16x2 a;
      a[0] = (f16)pd[2 * c];
      a[1] = (f16)pd[2 * c + 1];
      rW2d[c] = a;
      f16x2 bb;
      bb[0] = (f16)pg[2 * c];
      bb[1] = (f16)pg[2 * c + 1];
      rW2g[c] = bb;
    }
  }
  const float bias1 = (oq < 64) ? db1[oq] : gb1[oq - 64];
  const float bias2d = db2[oq], bias2g = gb2[oq];
  const float rB0 = bih[oq] + bhh[oq];
  const float rB1 = bih[oq + 128] + bhh[oq + 128];
  const float rBi2 = bih[oq + 256];
  const float rBh2 = bhh[oq + 256];

  // ---- state
  float h2e = 0.f, h1e = 0.f;
  if (kq == 0) sH2[oq] = (f16)0.f;

  const int xe = t;  // t<128 stages x
  const float* xbase = inputs + (size_t)b * H_LEN + xe;
  const size_t xstride = (size_t)B_LEN * H_LEN;
  float xreg = (t < H_LEN) ? xbase[0] : 0.f;

  __syncthreads();  // sZ, sDt/sSq/sU, sH2 init visible

  for (int i = 0; i < L; ++i) {
    if (t < H_LEN) sX[xe] = (f16)xreg;
    __syncthreads();  // A: sX + sH2 visible
    if (t < H_LEN && (i + 1) < NSTEP) xreg = xbase[(size_t)(i + 1) * xstride];

    // ---- GRU matvecs: 6 accumulators, 16-dot2 chains each
    float ai0 = 0.f, ai1 = 0.f, ai2 = 0.f;
    float ah0 = 0.f, ah1 = 0.f, ah2 = 0.f;
#pragma unroll
    for (int c = 0; c < 4; ++c) {
      const uint4 xv = *(const uint4*)&sX[kb32 + c * 8];
      const uint4 hv = *(const uint4*)&sH2[kb32 + c * 8];
      DOT4R(ai0, rWih[0], c * 4, xv);
      DOT4R(ai1, rWih[1], c * 4, xv);
      DOT4R(ai2, rWih[2], c * 4, xv);
      DOT4R(ah0, rWhh[0], c * 4, hv);
      DOT4R(ah1, rWhh[1], c * 4, hv);
      DOT4R(ah2, rWhh[2], c * 4, hv);
    }
#define QRED(v)          \
  v += __shfl_xor(v, 1); \
  v += __shfl_xor(v, 2)
    QRED(ai0);
    QRED(ai1);
    QRED(ai2);
    QRED(ah0);
    QRED(ah1);
    QRED(ah2);

    const float rg = fsig(ai0 + ah0 + rB0);
    const float zg = fsig(ai1 + ah1 + rB1);
    const float nn = ftanh_fast(ai2 + rBi2 + rg * (ah2 + rBh2));
    const float hg = (1.0f - zg) * nn + zg * h2e;
    float hh = hg;
    if (kq == 0) sH[oq] = (f16)hg;
    __syncthreads();  // B

    const float dt = sDt[i];
    const float sq = sSq[i];
    const float* zrow = &sZ[i * NSUB];
    for (int s = 0; s < NSUB; ++s) {
      // L1: a[oq] = (drift pre-tanh | diffusion pre-softplus)
      float a0 = 0.f, a1 = 0.f;
#pragma unroll
      for (int c = 0; c < 2; ++c) {
        const uint4 hv0 = *(const uint4*)&sH[kb32 + c * 8];
        const uint4 hv1 = *(const uint4*)&sH[kb32 + 16 + c * 8];
        DOT4R(a0, rW1, c * 4, hv0);
        DOT4R(a1, rW1, 8 + c * 4, hv1);
      }
      float a = a0 + a1;
      QRED(a);
      const float av = a + bias1;
      const float act = (oq < 64) ? ftanh_fast(av) : fsoftplus(av);
      if (kq == 0) sAct[oq] = (f16)act;
      __syncthreads();
      // L2: f[oq], g[oq]; update hh
      float fa = 0.f, ga = 0.f;
#pragma unroll
      for (int c = 0; c < 2; ++c) {
        const uint4 tv = *(const uint4*)&sAct[kb16 + c * 8];
        const uint4 sv = *(const uint4*)&sAct[64 + kb16 + c * 8];
        DOT4R(fa, rW2d, c * 4, tv);
        DOT4R(ga, rW2g, c * 4, sv);
      }
      QRED(fa);
      QRED(ga);
      hh += (fa + bias2d) * dt + (ga + bias2g) * (sq * zrow[s]);
      if (kq == 0) sH[oq] = (f16)hh;
      __syncthreads();
    }
#undef QRED

    // ---- h1/h2 update
    h2e = (i == 0) ? hg : (sU[i] * hg + (1.0f - sU[i]) * h1e);
    h1e = hh;
    if (kq == 0) sH2[oq] = (f16)h2e;
  }

  if (kq == 0) out[(size_t)b * H_LEN + oq] = h2e;
}

extern "C" void kernel_launch(void* const* d_in, const int* in_sizes, int n_in,
                              void* d_out, int out_size, void* d_ws,
                              size_t ws_size, hipStream_t stream) {
  (void)in_sizes;
  (void)n_in;
  (void)out_size;
  (void)ws_size;
  const float* inputs = (const float*)d_in[0];
  const float* times = (const float*)d_in[1];
  const int* non_zero = (const int*)d_in[2];
  const float* Wih = (const float*)d_in[3];
  const float* Whh = (const float*)d_in[4];
  const float* bih = (const float*)d_in[5];
  const float* bhh = (const float*)d_in[6];
  const float* dW1 = (const float*)d_in[7];
  const float* db1 = (const float*)d_in[8];
  const float* dW2 = (const float*)d_in[9];
  const float* db2 = (const float*)d_in[10];
  const float* gW1 = (const float*)d_in[11];
  const float* gb1 = (const float*)d_in[12];
  const float* gW2 = (const float*)d_in[13];
  const float* gb2 = (const float*)d_in[14];
  float* out = (float*)d_out;
  float* wsTd = (float*)d_ws;

  hipLaunchKernelGGL(td_kernel, dim3(NSTEP), dim3(256), 0, stream, times,
                     non_zero, wsTd);
  hipLaunchKernelGGL(sde_fused_kernel, dim3(B_LEN), dim3(512), 0, stream,
                     inputs, non_zero, Wih, Whh, bih, bhh, dW1, db1, dW2, db2,
                     gW1, gb1, gW2, gb2, wsTd, out);
}